// Round 5
// baseline (240.983 us; speedup 1.0000x reference)
//
#include <hip/hip_runtime.h>

// Butterfly multiply (untied), n=1024, 10 stages, increasing stride, + bias.
//
// R5: lane = ROW mapping. Block = 1024 threads = 16 waves; wave w = chunk w
// (columns [64w, 64w+64)); lane l = row (tile of 64 rows). Thread holds its
// 64-float chunk in registers the whole time.
//   - Twiddle indices depend only on (stage, chunk) -> wave-uniform ->
//     scalar s_load broadcast (no per-lane twiddle VMEM at all).
//   - Stages 0..5 (stride 1..32): in-thread. Stage-ls pairs of chunk w are
//     pair ids [32w, 32w+32) -> 128 contiguous scalar floats per stage.
//   - Stages 6..9 (stride 64..512): partner thread = (w ^ mask, same lane),
//     same slot index. Exchange via LDS in 4 slot-slices of 16 floats
//     (64 KB buffer), float4 ops swizzled Q ^= (l>>1)&3  -> conflict-free.
//   - Global I/O through LDS transpose slices (64 rows x 256 cols = 64 KB),
//     swizzle slot ^= (row&7): HBM side perfectly coalesced dwordx4, LDS
//     side conflict-free permuted access.
// VGPR budget: v[64] + ~40 temps < 128 cap of a 16-wave block -> no spill.

constexpr int N  = 1024;
constexpr int TR = 64;    // tile rows (= lanes)

__global__ __launch_bounds__(1024)
void butterfly_kernel(const float* __restrict__ x,
                      const float* __restrict__ tw,
                      const float* __restrict__ bias,
                      float* __restrict__ out,
                      int batch)
{
    __shared__ __align__(16) float lds[16384];   // 64 KB, reused per phase

    const int tid = (int)threadIdx.x;
    const int l   = tid & 63;                    // row within tile
    const int w   = tid >> 6;                    // chunk / wave id (0..15)
    const int wu  = __builtin_amdgcn_readfirstlane(w);  // uniform copy
    const int row0 = (int)blockIdx.x * TR;

    float v[64];
    float4* const ex = reinterpret_cast<float4*>(lds);

    // ================= IN: global -> LDS (swizzled) -> registers ==========
    float4 tmp[4];
    {
        // prefetch slice 0
        #pragma unroll
        for (int kk = 0; kk < 4; ++kk) {
            const int R = w * 4 + kk;
            int row = row0 + R; if (row >= batch) row = batch - 1;
            tmp[kk] = reinterpret_cast<const float4*>(x + (size_t)row * N)[l];
        }
        #pragma unroll
        for (int s = 0; s < 4; ++s) {
            __syncthreads();
            #pragma unroll
            for (int kk = 0; kk < 4; ++kk) {
                const int R = w * 4 + kk;
                ex[R * 64 + (l ^ (R & 7))] = tmp[kk];   // swizzled slot
            }
            __syncthreads();
            if (s < 3) {
                #pragma unroll
                for (int kk = 0; kk < 4; ++kk) {
                    const int R = w * 4 + kk;
                    int row = row0 + R; if (row >= batch) row = batch - 1;
                    tmp[kk] = reinterpret_cast<const float4*>(
                        x + (size_t)row * N + (s + 1) * 256)[l];
                }
            }
            if ((w >> 2) == s) {                        // my chunk is in this slice
                #pragma unroll
                for (int q = 0; q < 16; ++q) {
                    const int quad = (w & 3) * 16 + q;
                    const float4 t = ex[l * 64 + (quad ^ (l & 7))];
                    v[q*4+0] = t.x; v[q*4+1] = t.y;
                    v[q*4+2] = t.z; v[q*4+3] = t.w;
                }
            }
        }
    }

    // ================= stages 0..5: in-thread, scalar twiddles =============
    // pair ids for chunk w at stage ls = [32w, 32w+32); local elements:
    // k0 = ((p>>ls)<<(ls+1)) | (p & ((1<<ls)-1)), k1 = k0 + (1<<ls)
    #define INTH(LS)                                                         \
    {                                                                        \
        const int tb = (LS) * 2048 + wu * 128;                               \
        _Pragma("unroll")                                                    \
        for (int p = 0; p < 32; ++p) {                                       \
            const int k0 = ((p >> (LS)) << ((LS) + 1)) | (p & ((1 << (LS)) - 1)); \
            const int k1 = k0 + (1 << (LS));                                 \
            const float t0 = tw[tb + p*4 + 0], t1 = tw[tb + p*4 + 1];        \
            const float t2 = tw[tb + p*4 + 2], t3 = tw[tb + p*4 + 3];        \
            const float a = v[k0], b = v[k1];                                \
            v[k0] = t0 * a + t1 * b;                                         \
            v[k1] = t2 * a + t3 * b;                                         \
        }                                                                    \
    }
    INTH(0) INTH(1) INTH(2) INTH(3) INTH(4) INTH(5)
    #undef INTH

    // ================= stages 6..9: cross-chunk via LDS exchange ===========
    // partner chunk = w ^ MASK; pair = P0(w) + k; own-coeff = tw4[ipos*3],
    // partner-coeff = tw4[1+ipos]   (tw4 = [t00,t01,t10,t11])
    #define CROSS(LS, MASK)                                                  \
    {                                                                        \
        const int P0   = ((wu >> ((LS) - 5)) << (LS))                        \
                       + (wu & ((1 << ((LS) - 6)) - 1)) * 64;                \
        const int ipos = (wu >> ((LS) - 6)) & 1;                             \
        const int tb   = (LS) * 2048 + P0 * 4;                               \
        _Pragma("unroll")                                                    \
        for (int sl = 0; sl < 4; ++sl) {                                     \
            __syncthreads();                                                 \
            _Pragma("unroll")                                                \
            for (int Q = 0; Q < 4; ++Q) {                                    \
                const int k = sl * 16 + Q * 4;                               \
                ex[w * 256 + l * 4 + (Q ^ ((l >> 1) & 3))] =                 \
                    make_float4(v[k], v[k+1], v[k+2], v[k+3]);               \
            }                                                                \
            __syncthreads();                                                 \
            float4 pq[4];                                                    \
            _Pragma("unroll")                                                \
            for (int Q = 0; Q < 4; ++Q)                                      \
                pq[Q] = ex[(w ^ (MASK)) * 256 + l * 4 + (Q ^ ((l >> 1) & 3))]; \
            _Pragma("unroll")                                                \
            for (int t = 0; t < 16; ++t) {                                   \
                const int k = sl * 16 + t;                                   \
                const float4 P = pq[t >> 2];                                 \
                const float pa = (t & 3) == 0 ? P.x : (t & 3) == 1 ? P.y     \
                               : (t & 3) == 2 ? P.z : P.w;                   \
                const float co = tw[tb + k*4 + ipos*3];                      \
                const float cp = tw[tb + k*4 + 1 + ipos];                    \
                v[k] = co * v[k] + cp * pa;                                  \
            }                                                                \
        }                                                                    \
    }
    CROSS(6, 1) CROSS(7, 2) CROSS(8, 4) CROSS(9, 8)
    #undef CROSS

    // ================= bias (scalar) =======================================
    #pragma unroll
    for (int k = 0; k < 64; ++k) v[k] += bias[wu * 64 + k];

    // ================= OUT: registers -> LDS (swizzled) -> global ==========
    #pragma unroll
    for (int s = 0; s < 4; ++s) {
        __syncthreads();
        if ((w >> 2) == s) {
            #pragma unroll
            for (int q = 0; q < 16; ++q) {
                const int quad = (w & 3) * 16 + q;
                ex[l * 64 + (quad ^ (l & 7))] =
                    make_float4(v[q*4], v[q*4+1], v[q*4+2], v[q*4+3]);
            }
        }
        __syncthreads();
        #pragma unroll
        for (int kk = 0; kk < 4; ++kk) {
            const int R = w * 4 + kk;
            const float4 t = ex[R * 64 + (l ^ (R & 7))];
            if (row0 + R < batch)
                reinterpret_cast<float4*>(out + (size_t)(row0 + R) * N + s * 256)[l] = t;
        }
    }
}

extern "C" void kernel_launch(void* const* d_in, const int* in_sizes, int n_in,
                              void* d_out, int out_size, void* d_ws, size_t ws_size,
                              hipStream_t stream)
{
    (void)n_in; (void)d_ws; (void)ws_size; (void)out_size;
    const float* x    = (const float*)d_in[0];
    const float* tw   = (const float*)d_in[1];
    const float* bias = (const float*)d_in[2];
    float* out        = (float*)d_out;

    const int batch  = in_sizes[0] / N;
    const int blocks = (batch + TR - 1) / TR;      // 512 for batch=32768
    hipLaunchKernelGGL(butterfly_kernel, dim3(blocks), dim3(1024), 0, stream,
                       x, tw, bias, out, batch);
}

// Round 6
// 231.720 us; speedup vs baseline: 1.0400x; 1.0400x over previous
//
#include <hip/hip_runtime.h>

// Butterfly multiply (untied), n=1024, 10 stages, increasing stride, + bias.
//
// R6 = R5 structure with the register cap fixed. A 1024-thread block is 16
// waves = 4 waves/SIMD necessarily, so the VGPR ceiling is 128; plain
// __launch_bounds__(1024) made the compiler aim for 8 waves/EU -> 64 VGPRs
// -> v[64] spilled (R5: 227 MB scratch writes). amdgpu_waves_per_eu(4,4)
// pins 4 waves/EU -> allocator gets all 128 VGPRs; live state ~100 -> no spill.
//
// Mapping: wave w = chunk (columns [64w, 64w+64)), lane l = row. Thread holds
// its 64-float chunk in registers end-to-end.
//   - Twiddle indices depend only on (stage, chunk) -> wave-uniform ->
//     scalar s_load broadcast (no per-lane twiddle traffic).
//   - Stages 0..5: in-thread (pairs [32w,32w+32) per stage).
//   - Stages 6..9: partner thread = (w ^ mask, same lane); exchange via LDS
//     in 4 slot-slices of 16 floats (64 KB), float4 swizzled Q ^= (l>>1)&3.
//   - Global I/O through LDS transpose slices (swizzle quad ^= row&7):
//     HBM side perfectly coalesced dwordx4, LDS side conflict-free.

constexpr int N  = 1024;
constexpr int TR = 64;    // tile rows (= lanes)

__global__ __attribute__((amdgpu_flat_work_group_size(1024, 1024),
                          amdgpu_waves_per_eu(4, 4)))
void butterfly_kernel(const float* __restrict__ x,
                      const float* __restrict__ tw,
                      const float* __restrict__ bias,
                      float* __restrict__ out,
                      int batch)
{
    __shared__ __align__(16) float lds[16384];   // 64 KB, reused per phase

    const int tid = (int)threadIdx.x;
    const int l   = tid & 63;                    // row within tile
    const int w   = tid >> 6;                    // chunk / wave id (0..15)
    const int wu  = __builtin_amdgcn_readfirstlane(w);  // uniform copy
    const int row0 = (int)blockIdx.x * TR;

    float v[64];
    float4* const ex = reinterpret_cast<float4*>(lds);

    // ================= IN: global -> LDS (swizzled) -> registers ==========
    float4 tmp[4];
    {
        // prefetch slice 0
        #pragma unroll
        for (int kk = 0; kk < 4; ++kk) {
            const int R = w * 4 + kk;
            int row = row0 + R; if (row >= batch) row = batch - 1;
            tmp[kk] = reinterpret_cast<const float4*>(x + (size_t)row * N)[l];
        }
        #pragma unroll
        for (int s = 0; s < 4; ++s) {
            __syncthreads();
            #pragma unroll
            for (int kk = 0; kk < 4; ++kk) {
                const int R = w * 4 + kk;
                ex[R * 64 + (l ^ (R & 7))] = tmp[kk];   // swizzled slot
            }
            __syncthreads();
            if (s < 3) {
                #pragma unroll
                for (int kk = 0; kk < 4; ++kk) {
                    const int R = w * 4 + kk;
                    int row = row0 + R; if (row >= batch) row = batch - 1;
                    tmp[kk] = reinterpret_cast<const float4*>(
                        x + (size_t)row * N + (s + 1) * 256)[l];
                }
            }
            if ((w >> 2) == s) {                        // my chunk is in this slice
                #pragma unroll
                for (int q = 0; q < 16; ++q) {
                    const int quad = (w & 3) * 16 + q;
                    const float4 t = ex[l * 64 + (quad ^ (l & 7))];
                    v[q*4+0] = t.x; v[q*4+1] = t.y;
                    v[q*4+2] = t.z; v[q*4+3] = t.w;
                }
            }
        }
    }

    // ================= stages 0..5: in-thread, scalar twiddles =============
    // pair ids for chunk w at stage ls = [32w, 32w+32); local elements:
    // k0 = ((p>>ls)<<(ls+1)) | (p & ((1<<ls)-1)), k1 = k0 + (1<<ls)
    #define INTH(LS)                                                         \
    {                                                                        \
        const int tb = (LS) * 2048 + wu * 128;                               \
        _Pragma("unroll")                                                    \
        for (int p = 0; p < 32; ++p) {                                       \
            const int k0 = ((p >> (LS)) << ((LS) + 1)) | (p & ((1 << (LS)) - 1)); \
            const int k1 = k0 + (1 << (LS));                                 \
            const float t0 = tw[tb + p*4 + 0], t1 = tw[tb + p*4 + 1];        \
            const float t2 = tw[tb + p*4 + 2], t3 = tw[tb + p*4 + 3];        \
            const float a = v[k0], b = v[k1];                                \
            v[k0] = t0 * a + t1 * b;                                         \
            v[k1] = t2 * a + t3 * b;                                         \
        }                                                                    \
    }
    INTH(0) INTH(1) INTH(2) INTH(3) INTH(4) INTH(5)
    #undef INTH

    // ================= stages 6..9: cross-chunk via LDS exchange ===========
    // partner chunk = w ^ MASK; pair = P0(w) + k; own-coeff = tw4[ipos*3],
    // partner-coeff = tw4[1+ipos]   (tw4 = [t00,t01,t10,t11])
    #define CROSS(LS, MASK)                                                  \
    {                                                                        \
        const int P0   = ((wu >> ((LS) - 5)) << (LS))                        \
                       + (wu & ((1 << ((LS) - 6)) - 1)) * 64;                \
        const int ipos = (wu >> ((LS) - 6)) & 1;                             \
        const int tb   = (LS) * 2048 + P0 * 4;                               \
        _Pragma("unroll")                                                    \
        for (int sl = 0; sl < 4; ++sl) {                                     \
            __syncthreads();                                                 \
            _Pragma("unroll")                                                \
            for (int Q = 0; Q < 4; ++Q) {                                    \
                const int k = sl * 16 + Q * 4;                               \
                ex[w * 256 + l * 4 + (Q ^ ((l >> 1) & 3))] =                 \
                    make_float4(v[k], v[k+1], v[k+2], v[k+3]);               \
            }                                                                \
            __syncthreads();                                                 \
            float4 pq[4];                                                    \
            _Pragma("unroll")                                                \
            for (int Q = 0; Q < 4; ++Q)                                      \
                pq[Q] = ex[(w ^ (MASK)) * 256 + l * 4 + (Q ^ ((l >> 1) & 3))]; \
            _Pragma("unroll")                                                \
            for (int t = 0; t < 16; ++t) {                                   \
                const int k = sl * 16 + t;                                   \
                const float4 P = pq[t >> 2];                                 \
                const float pa = (t & 3) == 0 ? P.x : (t & 3) == 1 ? P.y     \
                               : (t & 3) == 2 ? P.z : P.w;                   \
                const float co = tw[tb + k*4 + ipos*3];                      \
                const float cp = tw[tb + k*4 + 1 + ipos];                    \
                v[k] = co * v[k] + cp * pa;                                  \
            }                                                                \
        }                                                                    \
    }
    CROSS(6, 1) CROSS(7, 2) CROSS(8, 4) CROSS(9, 8)
    #undef CROSS

    // ================= bias (scalar) =======================================
    #pragma unroll
    for (int k = 0; k < 64; ++k) v[k] += bias[wu * 64 + k];

    // ================= OUT: registers -> LDS (swizzled) -> global ==========
    #pragma unroll
    for (int s = 0; s < 4; ++s) {
        __syncthreads();
        if ((w >> 2) == s) {
            #pragma unroll
            for (int q = 0; q < 16; ++q) {
                const int quad = (w & 3) * 16 + q;
                ex[l * 64 + (quad ^ (l & 7))] =
                    make_float4(v[q*4], v[q*4+1], v[q*4+2], v[q*4+3]);
            }
        }
        __syncthreads();
        #pragma unroll
        for (int kk = 0; kk < 4; ++kk) {
            const int R = w * 4 + kk;
            const float4 t = ex[R * 64 + (l ^ (R & 7))];
            if (row0 + R < batch)
                reinterpret_cast<float4*>(out + (size_t)(row0 + R) * N + s * 256)[l] = t;
        }
    }
}

extern "C" void kernel_launch(void* const* d_in, const int* in_sizes, int n_in,
                              void* d_out, int out_size, void* d_ws, size_t ws_size,
                              hipStream_t stream)
{
    (void)n_in; (void)d_ws; (void)ws_size; (void)out_size;
    const float* x    = (const float*)d_in[0];
    const float* tw   = (const float*)d_in[1];
    const float* bias = (const float*)d_in[2];
    float* out        = (float*)d_out;

    const int batch  = in_sizes[0] / N;
    const int blocks = (batch + TR - 1) / TR;      // 512 for batch=32768
    hipLaunchKernelGGL(butterfly_kernel, dim3(blocks), dim3(1024), 0, stream,
                       x, tw, bias, out, batch);
}